// Round 3
// baseline (5132.609 us; speedup 1.0000x reference)
//
#include <hip/hip_runtime.h>

#define BB 512
#define TT 256

typedef __attribute__((ext_vector_type(8))) short bf16x8;
typedef __attribute__((ext_vector_type(4))) float f32x4;

__device__ __forceinline__ unsigned short f2b(float f) {
    union { float f; unsigned u; } v; v.f = f;
    unsigned r = v.u + 0x7FFFu + ((v.u >> 16) & 1u);  // round-to-nearest-even
    return (unsigned short)(r >> 16);
}
__device__ __forceinline__ float b2f(unsigned short h) {
    union { unsigned u; float f; } v; v.u = ((unsigned)h) << 16;
    return v.f;
}

// ---------------- fp32 -> bf16 convert (x input) ----------------
__global__ __launch_bounds__(256) void cvt_kernel(const float* __restrict__ x,
                                                  unsigned short* __restrict__ xb, int n4) {
    int i = blockIdx.x * 256 + threadIdx.x;
    if (i >= n4) return;
    float4 v = reinterpret_cast<const float4*>(x)[i];
    ushort4 o;
    o.x = f2b(v.x); o.y = f2b(v.y); o.z = f2b(v.z); o.w = f2b(v.w);
    reinterpret_cast<ushort4*>(xb)[i] = o;
}

// ---------------- input-projection GEMM (operand-swapped) ----------------
// Computes XP^T tiles: A = W^T (m = out-col), B = x rows (n = batch-row).
// D-fragment: lane holds (n = batch l15, m = ntg*16 + quad*4 + reg).
// XP out tile (s,t,ntg) at ((s*T+t)*(N/16)+ntg)*256, elem lane*4+reg — matches rec.
template<int K, int N>
__global__ __launch_bounds__(256, 2) void gemm_xp(const unsigned short* __restrict__ A,
                                                  const float* __restrict__ W,
                                                  const float* __restrict__ bias,
                                                  unsigned short* __restrict__ XP) {
    constexpr int NT = N / 64;   // m-tiles per wave
    constexpr int KC = K / 32;   // k-chunks
    __shared__ unsigned short WT[N * K];
    const int tid = threadIdx.x;
    // stage W transposed+swizzled: elem (k,n) -> WT[n*K + ((ch^(n&7))<<3) + (k&7)]
    for (int idx = tid; idx < K * N; idx += 256) {
        int k = idx / N, n = idx % N;
        int ch = k >> 3;
        WT[n * K + (((ch ^ (n & 7)) << 3) | (k & 7))] = f2b(W[idx]);
    }
    __syncthreads();
    const int s   = blockIdx.x >> 6;   // 0..31 b-slice
    const int t4  = blockIdx.x & 63;   // 0..63 t-group (4 t's)
    const int w   = tid >> 6;
    const int lane = tid & 63;
    const int l15 = lane & 15;
    const int quad = lane >> 4;

    f32x4 acc[4][NT];
#pragma unroll
    for (int mt = 0; mt < 4; ++mt)
#pragma unroll
        for (int nt = 0; nt < NT; ++nt) acc[mt][nt] = (f32x4)(0.0f);

#pragma unroll
    for (int kc = 0; kc < KC; ++kc) {
        bf16x8 bfr[NT];   // A-frags: W^T[m = wcol+nt*16+l15][k = kc*32+quad*8+j]
        const int ch = kc * 4 + quad;
#pragma unroll
        for (int nt = 0; nt < NT; ++nt) {
            int n = w * (N / 4) + nt * 16 + l15;
            bfr[nt] = *reinterpret_cast<const bf16x8*>(&WT[n * K + ((ch ^ (n & 7)) << 3)]);
        }
#pragma unroll
        for (int mt = 0; mt < 4; ++mt) {
            int row = (s * 16 + l15) * TT + (t4 * 4 + mt);
            bf16x8 bf = *reinterpret_cast<const bf16x8*>(&A[(size_t)row * K + kc * 32 + quad * 8]);
#pragma unroll
            for (int nt = 0; nt < NT; ++nt)
                acc[mt][nt] = __builtin_amdgcn_mfma_f32_16x16x32_bf16(bfr[nt], bf, acc[mt][nt], 0, 0, 0);
        }
    }
#pragma unroll
    for (int mt = 0; mt < 4; ++mt) {
        int t = t4 * 4 + mt;
#pragma unroll
        for (int nt = 0; nt < NT; ++nt) {
            int ntg = w * NT + nt;
            float4 bv = reinterpret_cast<const float4*>(bias)[ntg * 4 + quad];
            size_t base = ((size_t)(s * TT + t) * (N / 16) + ntg) * 256;
            ushort4 o;
            o.x = f2b(acc[mt][nt][0] + bv.x);
            o.y = f2b(acc[mt][nt][1] + bv.y);
            o.z = f2b(acc[mt][nt][2] + bv.z);
            o.w = f2b(acc[mt][nt][3] + bv.w);
            *reinterpret_cast<ushort4*>(&XP[base + (size_t)lane * 4]) = o;
        }
    }
}

// ---------------- recurrence: h_t = relu(xp_t + h_{t-1} @ Wh) ----------------
// A = Wh^T (m = out-col, frags permanent in VGPRs), B = h^T (n = batch).
// WAVES=4 (H=256): waves split out-cols; raw lgkm-only barrier per step keeps
//   global loads/stores in flight across steps. WAVES=1 (H<=128): single wave
//   owns all cols — NO barrier (per-wave DS ops are in-order).
// XP prefetched 2 steps ahead (register ring) to cover HBM miss latency.
// h_{t-1} written back to global straight from the af regs (they hold it).
template<int H, int WAVES>
__global__ __launch_bounds__(WAVES * 64, 1) void rec_kernel(const unsigned short* __restrict__ XP,
                                                            const float* __restrict__ Wh,
                                                            unsigned short* __restrict__ Hout) {
    constexpr int KC  = H / 32;
    constexpr int MT  = H / (16 * WAVES);   // m-tiles per wave
    constexpr int KCW = KC / WAVES;         // kc slices written back per wave
    constexpr int HP  = H + 8;
    __shared__ unsigned short hbuf[2][16 * HP];
    const int tid = threadIdx.x;
    const int s = blockIdx.x;          // b-slice 0..31
    const int w = tid >> 6;
    const int lane = tid & 63;
    const int l15 = lane & 15;
    const int quad = lane >> 4;
    const int colbase = w * (H / WAVES);

    // one-time: Wh^T A-fragments (fp32 global -> bf16)
    bf16x8 wh[KC][MT];
#pragma unroll
    for (int kc = 0; kc < KC; ++kc)
#pragma unroll
        for (int mt = 0; mt < MT; ++mt) {
            int m = colbase + mt * 16 + l15;
#pragma unroll
            for (int j = 0; j < 8; ++j)
                wh[kc][mt][j] = (short)f2b(Wh[(kc * 32 + quad * 8 + j) * H + m]);
        }

    for (int i = tid; i < 16 * HP; i += WAVES * 64) hbuf[0][i] = 0;
    __syncthreads();

    const unsigned short* XPs = XP + (size_t)s * TT * (H / 16) * 256;

    // xp register ring: xp0 = xp(t), xp1 = xp(t+1), xp2 = loading xp(t+2)
    ushort4 xp0[MT], xp1[MT], xp2[MT];
#pragma unroll
    for (int mt = 0; mt < MT; ++mt) {
        xp0[mt] = reinterpret_cast<const ushort4*>(&XPs[(size_t)(0 * (H / 16) + (w * MT + mt)) * 256])[lane];
        xp1[mt] = reinterpret_cast<const ushort4*>(&XPs[(size_t)(1 * (H / 16) + (w * MT + mt)) * 256])[lane];
    }

#pragma unroll 1
    for (int t = 0; t < TT; ++t) {
        const unsigned short* hr = hbuf[t & 1];
        unsigned short* hw = hbuf[(t + 1) & 1];

        // B-frags: h_{t-1}[n = batch l15][k = kc*32+quad*8+j]
        bf16x8 af[KC];
#pragma unroll
        for (int kc = 0; kc < KC; ++kc)
            af[kc] = *reinterpret_cast<const bf16x8*>(&hr[l15 * HP + kc * 32 + quad * 8]);

        // prefetch xp(t+2) — lands 2 steps from now
        if (t + 2 < TT) {
#pragma unroll
            for (int mt = 0; mt < MT; ++mt)
                xp2[mt] = reinterpret_cast<const ushort4*>(
                    &XPs[((size_t)(t + 2) * (H / 16) + (w * MT + mt)) * 256])[lane];
        }

        // writeback h_{t-1} straight from af regs (fire-and-forget stores)
        if (t >= 1) {
#pragma unroll
            for (int i = 0; i < KCW; ++i) {
                int kc = w * KCW + i;
                size_t g = ((size_t)(s * 16 + l15) * TT + (t - 1)) * H + kc * 32 + quad * 8;
                *reinterpret_cast<bf16x8*>(&Hout[g]) = af[kc];
            }
        }

        f32x4 accA[MT], accB[MT];
#pragma unroll
        for (int mt = 0; mt < MT; ++mt) { accA[mt] = (f32x4)(0.0f); accB[mt] = (f32x4)(0.0f); }
#pragma unroll
        for (int kc = 0; kc < KC; ++kc)
#pragma unroll
            for (int mt = 0; mt < MT; ++mt) {
                if (kc & 1)
                    accB[mt] = __builtin_amdgcn_mfma_f32_16x16x32_bf16(wh[kc][mt], af[kc], accB[mt], 0, 0, 0);
                else
                    accA[mt] = __builtin_amdgcn_mfma_f32_16x16x32_bf16(wh[kc][mt], af[kc], accA[mt], 0, 0, 0);
            }

        // epilogue: lane holds (batch l15, cols colbase+mt*16+quad*4+reg) -> 1 b64 write/tile
#pragma unroll
        for (int mt = 0; mt < MT; ++mt) {
            ushort4 o;
            o.x = f2b(fmaxf(accA[mt][0] + accB[mt][0] + b2f(xp0[mt].x), 0.f));
            o.y = f2b(fmaxf(accA[mt][1] + accB[mt][1] + b2f(xp0[mt].y), 0.f));
            o.z = f2b(fmaxf(accA[mt][2] + accB[mt][2] + b2f(xp0[mt].z), 0.f));
            o.w = f2b(fmaxf(accA[mt][3] + accB[mt][3] + b2f(xp0[mt].w), 0.f));
            *reinterpret_cast<ushort4*>(&hw[l15 * HP + colbase + mt * 16 + quad * 4]) = o;
        }
#pragma unroll
        for (int mt = 0; mt < MT; ++mt) { xp0[mt] = xp1[mt]; xp1[mt] = xp2[mt]; }

        if (WAVES > 1) {
            // lgkm-only drain + barrier: LDS coherent across waves, but global
            // loads/stores stay in flight (no vmcnt(0) stall per step).
            asm volatile("s_waitcnt lgkmcnt(0)\n\ts_barrier" ::: "memory");
        }
    }

    // final h_{TT-1} writeback
    {
        const unsigned short* hr = hbuf[TT & 1];
#pragma unroll
        for (int i = 0; i < KCW; ++i) {
            int kc = w * KCW + i;
            bf16x8 v = *reinterpret_cast<const bf16x8*>(&hr[l15 * HP + kc * 32 + quad * 8]);
            size_t g = ((size_t)(s * 16 + l15) * TT + (TT - 1)) * H + kc * 32 + quad * 8;
            *reinterpret_cast<bf16x8*>(&Hout[g]) = v;
        }
    }
}

// ---------------- final dense: out[b] = flat[b,:] . Wd + bd ----------------
__global__ __launch_bounds__(256) void dense_kernel(const unsigned short* __restrict__ Hb,
                                                    const float* __restrict__ Wd,
                                                    const float* __restrict__ bd,
                                                    float* __restrict__ out) {
    __shared__ float red[256];
    const int b = blockIdx.x;
    const int tid = threadIdx.x;
    const unsigned short* row = Hb + (size_t)b * (TT * 64);
    float acc = 0.f;
    for (int j = tid; j < TT * 64; j += 256)
        acc += b2f(row[j]) * Wd[j];
    red[tid] = acc;
    __syncthreads();
    for (int s2 = 128; s2 > 0; s2 >>= 1) {
        if (tid < s2) red[tid] += red[tid + s2];
        __syncthreads();
    }
    if (tid == 0) out[b] = red[0] + bd[0];
}

extern "C" void kernel_launch(void* const* d_in, const int* in_sizes, int n_in,
                              void* d_out, int out_size, void* d_ws, size_t ws_size,
                              hipStream_t stream) {
    (void)in_sizes; (void)n_in; (void)out_size; (void)ws_size;
    const float* x   = (const float*)d_in[0];
    const float* Wx1 = (const float*)d_in[1];
    const float* Wh1 = (const float*)d_in[2];
    const float* b1  = (const float*)d_in[3];
    const float* Wx2 = (const float*)d_in[4];
    const float* Wh2 = (const float*)d_in[5];
    const float* b2  = (const float*)d_in[6];
    const float* Wx3 = (const float*)d_in[7];
    const float* Wh3 = (const float*)d_in[8];
    const float* b3  = (const float*)d_in[9];
    const float* Wx4 = (const float*)d_in[10];
    const float* Wh4 = (const float*)d_in[11];
    const float* b4  = (const float*)d_in[12];
    const float* Wd  = (const float*)d_in[13];
    const float* bd  = (const float*)d_in[14];
    float* out = (float*)d_out;

    char* ws = (char*)d_ws;
    // layout (bytes): xb 16.8M | XP 67.1M | H0 67.1M | H1 67.1M  => 218.1M total
    unsigned short* xb = (unsigned short*)(ws);
    unsigned short* XP = (unsigned short*)(ws + 16777216);
    unsigned short* H0 = (unsigned short*)(ws + 16777216 + 67108864);
    unsigned short* H1 = (unsigned short*)(ws + 16777216 + 2 * 67108864);

    cvt_kernel<<<8192, 256, 0, stream>>>(x, xb, BB * TT * 64 / 4);

    gemm_xp<64, 128><<<2048, 256, 0, stream>>>(xb, Wx1, b1, XP);
    rec_kernel<128, 1><<<32, 64, 0, stream>>>(XP, Wh1, H0);

    gemm_xp<128, 256><<<2048, 256, 0, stream>>>(H0, Wx2, b2, XP);
    rec_kernel<256, 4><<<32, 256, 0, stream>>>(XP, Wh2, H1);

    gemm_xp<256, 128><<<2048, 256, 0, stream>>>(H1, Wx3, b3, XP);
    rec_kernel<128, 1><<<32, 64, 0, stream>>>(XP, Wh3, H0);

    gemm_xp<128, 64><<<2048, 256, 0, stream>>>(H0, Wx4, b4, XP);
    rec_kernel<64, 1><<<32, 64, 0, stream>>>(XP, Wh4, H1);

    dense_kernel<<<512, 256, 0, stream>>>(H1, Wd, bd, out);
}

// Round 4
// 872.241 us; speedup vs baseline: 5.8844x; 5.8844x over previous
//
#include <hip/hip_runtime.h>

#define BB 512
#define TT 256

typedef __attribute__((ext_vector_type(8))) short bf16x8;
typedef __attribute__((ext_vector_type(4))) float f32x4;

__device__ __forceinline__ unsigned short f2b(float f) {
    union { float f; unsigned u; } v; v.f = f;
    unsigned r = v.u + 0x7FFFu + ((v.u >> 16) & 1u);  // round-to-nearest-even
    return (unsigned short)(r >> 16);
}
__device__ __forceinline__ float b2f(unsigned short h) {
    union { unsigned u; float f; } v; v.u = ((unsigned)h) << 16;
    return v.f;
}

// ---------------- fp32 -> bf16 convert (x input) ----------------
__global__ __launch_bounds__(256) void cvt_kernel(const float* __restrict__ x,
                                                  unsigned short* __restrict__ xb, int n4) {
    int i = blockIdx.x * 256 + threadIdx.x;
    if (i >= n4) return;
    float4 v = reinterpret_cast<const float4*>(x)[i];
    ushort4 o;
    o.x = f2b(v.x); o.y = f2b(v.y); o.z = f2b(v.z); o.w = f2b(v.w);
    reinterpret_cast<ushort4*>(xb)[i] = o;
}

// ---------------- input-projection GEMM ----------------
// A: [B*T, K] bf16 row-major (row = b*T + t). W: [K,N] fp32. XP out: swizzled
// C-fragment tiles: tile (s,t,ntg) at ((s*T+t)*(N/16)+ntg)*256, elem lane*4+reg.
// Block = 256 thr (4 waves). Block covers b-slice s (16 rows) x 4 consecutive t.
// Waves split N in 4. W staged whole in LDS (bf16, XOR-swizzled, <=64KB).
template<int K, int N>
__global__ __launch_bounds__(256, 2) void gemm_xp(const unsigned short* __restrict__ A,
                                                  const float* __restrict__ W,
                                                  const float* __restrict__ bias,
                                                  unsigned short* __restrict__ XP) {
    constexpr int NT = N / 64;   // n-tiles per wave
    constexpr int KC = K / 32;   // k-chunks
    __shared__ unsigned short WT[N * K];
    const int tid = threadIdx.x;
    // stage W transposed+swizzled: elem (k,n) -> WT[n*K + ((ch^(n&7))<<3) + (k&7)]
    for (int idx = tid; idx < K * N; idx += 256) {
        int k = idx / N, n = idx % N;
        int ch = k >> 3;
        WT[n * K + (((ch ^ (n & 7)) << 3) | (k & 7))] = f2b(W[idx]);
    }
    __syncthreads();
    const int s   = blockIdx.x >> 6;   // 0..31 b-slice
    const int t4  = blockIdx.x & 63;   // 0..63 t-group (4 t's)
    const int w   = tid >> 6;
    const int lane = tid & 63;
    const int l15 = lane & 15;
    const int quad = lane >> 4;

    f32x4 acc[4][NT];
#pragma unroll
    for (int mt = 0; mt < 4; ++mt)
#pragma unroll
        for (int nt = 0; nt < NT; ++nt) acc[mt][nt] = (f32x4)(0.0f);

#pragma unroll
    for (int kc = 0; kc < KC; ++kc) {
        bf16x8 bfr[NT];
        const int ch = kc * 4 + quad;
#pragma unroll
        for (int nt = 0; nt < NT; ++nt) {
            int n = w * (N / 4) + nt * 16 + l15;
            bfr[nt] = *reinterpret_cast<const bf16x8*>(&WT[n * K + ((ch ^ (n & 7)) << 3)]);
        }
#pragma unroll
        for (int mt = 0; mt < 4; ++mt) {
            int row = (s * 16 + l15) * TT + (t4 * 4 + mt);
            bf16x8 af = *reinterpret_cast<const bf16x8*>(&A[(size_t)row * K + kc * 32 + quad * 8]);
#pragma unroll
            for (int nt = 0; nt < NT; ++nt)
                acc[mt][nt] = __builtin_amdgcn_mfma_f32_16x16x32_bf16(af, bfr[nt], acc[mt][nt], 0, 0, 0);
        }
    }
#pragma unroll
    for (int mt = 0; mt < 4; ++mt) {
        int t = t4 * 4 + mt;
#pragma unroll
        for (int nt = 0; nt < NT; ++nt) {
            int ntg = w * NT + nt;
            float bv = bias[ntg * 16 + l15];
            size_t base = ((size_t)(s * TT + t) * (N / 16) + ntg) * 256;
            ushort4 o;
            o.x = f2b(acc[mt][nt][0] + bv);
            o.y = f2b(acc[mt][nt][1] + bv);
            o.z = f2b(acc[mt][nt][2] + bv);
            o.w = f2b(acc[mt][nt][3] + bv);
            *reinterpret_cast<ushort4*>(&XP[base + (size_t)lane * 4]) = o;
        }
    }
}

// ---------------- recurrence: h_t = relu(xp_t + h_{t-1} @ Wh) ----------------
// 32 blocks (16 batch rows each), 256 thr = 4 waves, waves split H cols by 4.
// Wh fragments live in registers for the whole kernel. h state ping-pongs in
// LDS (bf16, padded stride). ONE raw lgkm-only barrier per step: cross-wave
// deps in the loop flow only through LDS, so global loads/stores stay in
// flight (no per-step vmcnt(0) drain — that was round-2's 2240 cyc/step).
template<int H>
__global__ __launch_bounds__(256, 1) void rec_kernel(const unsigned short* __restrict__ XP,
                                                     const float* __restrict__ Wh,
                                                     unsigned short* __restrict__ Hout) {
    constexpr int NT = H / 64;
    constexpr int KC = H / 32;
    constexpr int HP = H + 8;
    __shared__ unsigned short hbuf[2][16 * HP];
    const int tid = threadIdx.x;
    const int s = blockIdx.x;          // b-slice 0..31
    const int w = tid >> 6;
    const int lane = tid & 63;
    const int l15 = lane & 15;
    const int quad = lane >> 4;

    // one-time: gather Wh into register fragments (fp32 global -> bf16)
    bf16x8 wh[KC][NT];
#pragma unroll
    for (int kc = 0; kc < KC; ++kc)
#pragma unroll
        for (int nt = 0; nt < NT; ++nt) {
            int n = w * (H / 4) + nt * 16 + l15;
#pragma unroll
            for (int j = 0; j < 8; ++j) {
                int k = kc * 32 + quad * 8 + j;
                wh[kc][nt][j] = (short)f2b(Wh[k * H + n]);
            }
        }

    for (int i = tid; i < 16 * HP; i += 256) hbuf[0][i] = 0;
    __syncthreads();

    // prefetch xp for t=0
    ushort4 xpr[NT];
#pragma unroll
    for (int nt = 0; nt < NT; ++nt) {
        size_t base = ((size_t)(s * TT + 0) * (H / 16) + (w * NT + nt)) * 256;
        xpr[nt] = reinterpret_cast<const ushort4*>(&XP[base])[lane];
    }

#pragma unroll 1
    for (int t = 0; t < TT; ++t) {
        const unsigned short* hr = hbuf[t & 1];
        unsigned short* hw = hbuf[(t + 1) & 1];

        bf16x8 af[KC];
#pragma unroll
        for (int kc = 0; kc < KC; ++kc)
            af[kc] = *reinterpret_cast<const bf16x8*>(&hr[l15 * HP + kc * 32 + quad * 8]);

        // prefetch xp for t+1 (overlaps MFMA)
        ushort4 xpn[NT];
        if (t + 1 < TT) {
#pragma unroll
            for (int nt = 0; nt < NT; ++nt) {
                size_t base = ((size_t)(s * TT + (t + 1)) * (H / 16) + (w * NT + nt)) * 256;
                xpn[nt] = reinterpret_cast<const ushort4*>(&XP[base])[lane];
            }
        }

        f32x4 acc[NT];
#pragma unroll
        for (int nt = 0; nt < NT; ++nt) acc[nt] = (f32x4)(0.0f);
#pragma unroll
        for (int kc = 0; kc < KC; ++kc)
#pragma unroll
            for (int nt = 0; nt < NT; ++nt)
                acc[nt] = __builtin_amdgcn_mfma_f32_16x16x32_bf16(af[kc], wh[kc][nt], acc[nt], 0, 0, 0);

#pragma unroll
        for (int nt = 0; nt < NT; ++nt) {
            float v0 = fmaxf(acc[nt][0] + b2f(xpr[nt].x), 0.f);
            float v1 = fmaxf(acc[nt][1] + b2f(xpr[nt].y), 0.f);
            float v2 = fmaxf(acc[nt][2] + b2f(xpr[nt].z), 0.f);
            float v3 = fmaxf(acc[nt][3] + b2f(xpr[nt].w), 0.f);
            int col = w * (H / 4) + nt * 16 + l15;
            hw[(quad * 4 + 0) * HP + col] = f2b(v0);
            hw[(quad * 4 + 1) * HP + col] = f2b(v1);
            hw[(quad * 4 + 2) * HP + col] = f2b(v2);
            hw[(quad * 4 + 3) * HP + col] = f2b(v3);
        }
        // lgkm-only drain + barrier: all cross-wave deps in this loop are LDS;
        // global XP loads / Hout stores legally stay in flight across steps.
        asm volatile("s_waitcnt lgkmcnt(0)\n\ts_barrier" ::: "memory");

        // coalesced global writeback of h_t via LDS (off critical path)
        constexpr int CHUNKS = 16 * H / 8;      // 16B chunks
        for (int ci = tid; ci < CHUNKS; ci += 256) {
            int row = ci / (H / 8);
            int off = (ci % (H / 8)) * 8;
            uint4 v = *reinterpret_cast<const uint4*>(&hw[row * HP + off]);
            size_t g = ((size_t)(s * 16 + row) * TT + t) * H + off;
            *reinterpret_cast<uint4*>(&Hout[g]) = v;
        }

        if (t + 1 < TT) {
#pragma unroll
            for (int nt = 0; nt < NT; ++nt) xpr[nt] = xpn[nt];
        }
    }
}

// ---------------- final dense: out[b] = flat[b,:] . Wd + bd ----------------
__global__ __launch_bounds__(256) void dense_kernel(const unsigned short* __restrict__ Hb,
                                                    const float* __restrict__ Wd,
                                                    const float* __restrict__ bd,
                                                    float* __restrict__ out) {
    __shared__ float red[256];
    const int b = blockIdx.x;
    const int tid = threadIdx.x;
    const unsigned short* row = Hb + (size_t)b * (TT * 64);
    float acc = 0.f;
    for (int j = tid; j < TT * 64; j += 256)
        acc += b2f(row[j]) * Wd[j];
    red[tid] = acc;
    __syncthreads();
    for (int s2 = 128; s2 > 0; s2 >>= 1) {
        if (tid < s2) red[tid] += red[tid + s2];
        __syncthreads();
    }
    if (tid == 0) out[b] = red[0] + bd[0];
}

extern "C" void kernel_launch(void* const* d_in, const int* in_sizes, int n_in,
                              void* d_out, int out_size, void* d_ws, size_t ws_size,
                              hipStream_t stream) {
    (void)in_sizes; (void)n_in; (void)out_size; (void)ws_size;
    const float* x   = (const float*)d_in[0];
    const float* Wx1 = (const float*)d_in[1];
    const float* Wh1 = (const float*)d_in[2];
    const float* b1  = (const float*)d_in[3];
    const float* Wx2 = (const float*)d_in[4];
    const float* Wh2 = (const float*)d_in[5];
    const float* b2  = (const float*)d_in[6];
    const float* Wx3 = (const float*)d_in[7];
    const float* Wh3 = (const float*)d_in[8];
    const float* b3  = (const float*)d_in[9];
    const float* Wx4 = (const float*)d_in[10];
    const float* Wh4 = (const float*)d_in[11];
    const float* b4  = (const float*)d_in[12];
    const float* Wd  = (const float*)d_in[13];
    const float* bd  = (const float*)d_in[14];
    float* out = (float*)d_out;

    char* ws = (char*)d_ws;
    // layout (bytes): xb 16.8M | XP 67.1M | H0 67.1M | H1 67.1M  => 218.1M total
    unsigned short* xb = (unsigned short*)(ws);
    unsigned short* XP = (unsigned short*)(ws + 16777216);
    unsigned short* H0 = (unsigned short*)(ws + 16777216 + 67108864);
    unsigned short* H1 = (unsigned short*)(ws + 16777216 + 2 * 67108864);

    cvt_kernel<<<8192, 256, 0, stream>>>(x, xb, BB * TT * 64 / 4);

    gemm_xp<64, 128><<<2048, 256, 0, stream>>>(xb, Wx1, b1, XP);
    rec_kernel<128><<<32, 256, 0, stream>>>(XP, Wh1, H0);

    gemm_xp<128, 256><<<2048, 256, 0, stream>>>(H0, Wx2, b2, XP);
    rec_kernel<256><<<32, 256, 0, stream>>>(XP, Wh2, H1);

    gemm_xp<256, 128><<<2048, 256, 0, stream>>>(H1, Wx3, b3, XP);
    rec_kernel<128><<<32, 256, 0, stream>>>(XP, Wh3, H0);

    gemm_xp<128, 64><<<2048, 256, 0, stream>>>(H0, Wx4, b4, XP);
    rec_kernel<64><<<32, 256, 0, stream>>>(XP, Wh4, H1);

    dense_kernel<<<512, 256, 0, stream>>>(H1, Wd, bd, out);
}